// Round 2
// 1381.254 us; speedup vs baseline: 1.1813x; 1.1813x over previous
//
#include <hip/hip_runtime.h>

// Attention_26250840113588 — round 4 (resubmit; round-1 bench was an infra
// GPUAcquisitionTimeout, no measurement taken): kill the V-transpose LDS bank
// conflicts. rocprof showed SQ_LDS_BANK_CONFLICT=1.48e8 on attn_fwd (~25% of
// all CU cycles): the transposed V staging store had a 1152B (= 0 mod 128)
// per-lane stride -> 16-way conflict on every scalar bf16 write. Fix:
// XOR-swizzle the kv-block slot within each Vs row by (hd>>4). Write side now
// spreads 16 lanes over 8 banks (2-way = free); read side sees a wave-uniform
// XOR per fragment (hd>>4 == nf), so the b128 reads stay contiguous/aligned.
// Everything else unchanged from round 3.
//
// Pipeline: gemm_bt<0,1> (Q=x@wq^T*rope, bf16 out) -> attn_fwd (in-place)
//           -> gemm_bt<1,0> (out=O@wo^T, fp32 out)

typedef __attribute__((ext_vector_type(8))) __bf16 bf16x8;
typedef __attribute__((ext_vector_type(4))) float f32x4;

#define S_LEN 2048
#define DMODEL 4096
#define NKV 8
#define HD 128

__device__ __forceinline__ bf16x8 cvt8(const float* __restrict__ p) {
  float4 f0 = *(const float4*)p, f1 = *(const float4*)(p + 4);
  bf16x8 v;
  v[0] = (__bf16)f0.x; v[1] = (__bf16)f0.y; v[2] = (__bf16)f0.z; v[3] = (__bf16)f0.w;
  v[4] = (__bf16)f1.x; v[5] = (__bf16)f1.y; v[6] = (__bf16)f1.z; v[7] = (__bf16)f1.w;
  return v;
}

// ---------------- GEMM: C[M,N] = A[M,K] @ Bw[N,K]^T (M=N=K=4096) ----------------
// A_BF16: A is bf16 (ws buffer) else fp32 (converted during staging). Bw is fp32.
// EPI==1: C is bf16, fused rope scale C[row,col] *= freqs[(row%2048)*64 + (col&63)]
// EPI==0: C is fp32 (final output).
template <int A_BF16, int EPI>
__global__ __launch_bounds__(256) void gemm_bt(
    const void* __restrict__ Av, const float* __restrict__ Bw,
    void* __restrict__ Cv, const float* __restrict__ freqs) {
  __shared__ __attribute__((aligned(16))) __bf16 As[128 * 72];  // [m][k] stride 72
  __shared__ __attribute__((aligned(16))) __bf16 Bs[128 * 72];  // [n][k] stride 72
  const int t = threadIdx.x;
  const int wave = t >> 6, lane = t & 63;
  const int l15 = lane & 15, quad = lane >> 4;
  const int wm = wave >> 1, wn = wave & 1;
  const int m0 = blockIdx.y * 128, n0 = blockIdx.x * 128;
  f32x4 acc[4][4] = {};
  for (int k0 = 0; k0 < DMODEL; k0 += 64) {
#pragma unroll
    for (int i = 0; i < 4; ++i) {  // 128 rows x 64 cols, 8 elems/thread
      int c = i * 256 + t;
      int r = c >> 3, col8 = (c & 7) * 8;
      if (A_BF16) {
        *(float4*)&As[r * 72 + col8] =
            *(const float4*)&((const __bf16*)Av)[(size_t)(m0 + r) * DMODEL + k0 + col8];
      } else {
        *(bf16x8*)&As[r * 72 + col8] =
            cvt8(&((const float*)Av)[(size_t)(m0 + r) * DMODEL + k0 + col8]);
      }
      *(bf16x8*)&Bs[r * 72 + col8] =
          cvt8(&Bw[(size_t)(n0 + r) * DMODEL + k0 + col8]);
    }
    __syncthreads();
#pragma unroll
    for (int ks = 0; ks < 2; ++ks) {
      bf16x8 af[4], bfr[4];
#pragma unroll
      for (int i = 0; i < 4; ++i) {
        af[i]  = *(const bf16x8*)&As[(wm * 64 + i * 16 + l15) * 72 + ks * 32 + quad * 8];
        bfr[i] = *(const bf16x8*)&Bs[(wn * 64 + i * 16 + l15) * 72 + ks * 32 + quad * 8];
      }
#pragma unroll
      for (int mi = 0; mi < 4; ++mi)
#pragma unroll
        for (int ni = 0; ni < 4; ++ni)
          acc[mi][ni] = __builtin_amdgcn_mfma_f32_16x16x32_bf16(
              af[mi], bfr[ni], acc[mi][ni], 0, 0, 0);
    }
    __syncthreads();
  }
#pragma unroll
  for (int mi = 0; mi < 4; ++mi) {
    int rowb = m0 + wm * 64 + mi * 16 + quad * 4;
#pragma unroll
    for (int ni = 0; ni < 4; ++ni) {
      int col = n0 + wn * 64 + ni * 16 + l15;
#pragma unroll
      for (int r = 0; r < 4; ++r) {
        float v = acc[mi][ni][r];
        if (EPI == 1) {
          int s = (rowb + r) & (S_LEN - 1);
          v *= freqs[s * 64 + (col & 63)];
          ((__bf16*)Cv)[(size_t)(rowb + r) * DMODEL + col] = (__bf16)v;
        } else {
          ((float*)Cv)[(size_t)(rowb + r) * DMODEL + col] = v;
        }
      }
    }
  }
}

// ---------------- Flash attention (causal, GQA), Q/O in-place bf16 ----------------
// Block: (qt, h, b); 4 waves x 16 q-rows. KV tiles of 64, only kt <= qt.
// QO (bf16, ws) is (B,S,NH,HD): block reads its exclusive Q slice at start,
// writes O to the same slice at end. K,V are fp32 globals (cache_k/cache_v),
// converted to bf16 during LDS staging (V transposed in the same pass).
//
// Vs layout (bank-conflict-free transpose): element (kv, hd) lives at
//   Vs[hd*72 + ((kv>>3) ^ (hd>>4))*8 + (kv&7)]
// The XOR term is wave-uniform on the b128 fragment read (hd>>4 == nf) and
// lane-varying on the scalar transpose write (hd>>4 == l>>1), which breaks
// the former 16-way same-bank store pattern.
__global__ __launch_bounds__(256) void attn_fwd(
    __bf16* __restrict__ QO, const float* __restrict__ K,
    const float* __restrict__ V) {
  __shared__ __attribute__((aligned(16))) __bf16 Ks[64 * 136];   // [kv][hd] stride 136
  __shared__ __attribute__((aligned(16))) __bf16 Vs[128 * 72];   // [hd][kv-swizzled]
  __shared__ __attribute__((aligned(16))) __bf16 Ps[4][16 * 72]; // per-wave [q][kv]
  const int qt = blockIdx.x, h = blockIdx.y, b = blockIdx.z;
  const int g = h >> 2;  // NREP = 4
  const int t = threadIdx.x, wave = t >> 6, lane = t & 63;
  const int l15 = lane & 15, quad = lane >> 4;
  __bf16* qbase =
      QO + (size_t)(b * S_LEN + qt * 64 + wave * 16 + l15) * DMODEL + h * HD;
  bf16x8 qf[4];
#pragma unroll
  for (int kk = 0; kk < 4; ++kk) qf[kk] = *(const bf16x8*)&qbase[kk * 32 + quad * 8];
  f32x4 of[8] = {};
  float m_r[4], l_r[4];
#pragma unroll
  for (int r = 0; r < 4; ++r) { m_r[r] = -1e30f; l_r[r] = 0.f; }
  const float* kbase = K + ((size_t)b * S_LEN * NKV + g) * HD;
  const float* vbase = V + ((size_t)b * S_LEN * NKV + g) * HD;
  const float scale = 0.08838834764831845f;  // 1/sqrt(128)
  for (int kt = 0; kt <= qt; ++kt) {
    // stage K tile: 64 rows(kv) x 128 cols(hd), fp32 -> bf16
#pragma unroll
    for (int i = 0; i < 4; ++i) {
      int c = i * 256 + t, r = c >> 4, col8 = (c & 15) * 8;
      *(bf16x8*)&Ks[r * 136 + col8] =
          cvt8(&kbase[(size_t)(kt * 64 + r) * (NKV * HD) + col8]);
    }
    // stage V tile TRANSPOSED with kv-block XOR swizzle (see header comment)
#pragma unroll
    for (int i = 0; i < 4; ++i) {
      int c = i * 256 + t, r = c >> 4, col8 = (c & 15) * 8;
      bf16x8 vv = cvt8(&vbase[(size_t)(kt * 64 + r) * (NKV * HD) + col8]);
      const int rblk = r >> 3, rin = r & 7;
#pragma unroll
      for (int j = 0; j < 8; ++j) {
        const int hd = col8 + j;
        const int blk = (rblk ^ (hd >> 4)) & 7;
        Vs[hd * 72 + blk * 8 + rin] = vv[j];
      }
    }
    __syncthreads();
    // S = Q K^T  (wave: 16 q-rows x 64 kv-cols)
    f32x4 sf[4] = {};
#pragma unroll
    for (int kk = 0; kk < 4; ++kk)
#pragma unroll
      for (int ni = 0; ni < 4; ++ni) {
        bf16x8 kf = *(const bf16x8*)&Ks[(ni * 16 + l15) * 136 + kk * 32 + quad * 8];
        sf[ni] = __builtin_amdgcn_mfma_f32_16x16x32_bf16(qf[kk], kf, sf[ni], 0, 0, 0);
      }
    // online softmax per row (row quad*4+r lives in lanes quad*16 + 0..15)
    const int rowg = qt * 64 + wave * 16 + quad * 4;
#pragma unroll
    for (int r = 0; r < 4; ++r) {
      float sv[4];
#pragma unroll
      for (int ni = 0; ni < 4; ++ni) {
        float v = sf[ni][r] * scale;
        int col = kt * 64 + ni * 16 + l15;
        if (col > rowg + r) v = -1e9f;  // causal mask (== ref's -1e9 add)
        sv[ni] = v;
      }
      float mx = fmaxf(fmaxf(sv[0], sv[1]), fmaxf(sv[2], sv[3]));
#pragma unroll
      for (int off = 1; off < 16; off <<= 1) mx = fmaxf(mx, __shfl_xor(mx, off, 64));
      float mn = fmaxf(m_r[r], mx);
      float alpha = __expf(m_r[r] - mn);
      float sum = 0.f;
#pragma unroll
      for (int ni = 0; ni < 4; ++ni) {
        float p = __expf(sv[ni] - mn);
        sum += p;
        sf[ni][r] = p;
      }
#pragma unroll
      for (int off = 1; off < 16; off <<= 1) sum += __shfl_xor(sum, off, 64);
      l_r[r] = l_r[r] * alpha + sum;
      m_r[r] = mn;
#pragma unroll
      for (int nf = 0; nf < 8; ++nf) of[nf][r] *= alpha;
    }
    // P: C-layout -> per-wave LDS -> A-operand layout
#pragma unroll
    for (int ni = 0; ni < 4; ++ni)
#pragma unroll
      for (int r = 0; r < 4; ++r)
        Ps[wave][(quad * 4 + r) * 72 + ni * 16 + l15] = (__bf16)sf[ni][r];
    asm volatile("s_waitcnt lgkmcnt(0)" ::: "memory");
    // O += P V   (B-frag: Vs[hd][kv-swizzled], k(=kv)-contiguous within block)
#pragma unroll
    for (int kb = 0; kb < 2; ++kb) {
      bf16x8 pf = *(const bf16x8*)&Ps[wave][l15 * 72 + kb * 32 + quad * 8];
#pragma unroll
      for (int nf = 0; nf < 8; ++nf) {
        const int hd = nf * 16 + l15;
        const int blk = ((kb * 4 + quad) ^ (hd >> 4)) & 7;
        bf16x8 vf = *(const bf16x8*)&Vs[hd * 72 + blk * 8];
        of[nf] = __builtin_amdgcn_mfma_f32_16x16x32_bf16(pf, vf, of[nf], 0, 0, 0);
      }
    }
    __syncthreads();
  }
  // write O over Q (same exclusive slice)
#pragma unroll
  for (int r = 0; r < 4; ++r) {
    float inv = 1.0f / l_r[r];
    size_t row = (size_t)(b * S_LEN + qt * 64 + quad * 4 + wave * 16 + r);
#pragma unroll
    for (int nf = 0; nf < 8; ++nf)
      QO[row * DMODEL + h * HD + nf * 16 + l15] = (__bf16)(of[nf][r] * inv);
  }
}

extern "C" void kernel_launch(void* const* d_in, const int* in_sizes, int n_in,
                              void* d_out, int out_size, void* d_ws, size_t ws_size,
                              hipStream_t stream) {
  const float* x     = (const float*)d_in[0];
  const float* freqs = (const float*)d_in[1];
  // d_in[2] mask: applied analytically (triu(-1e9, k=1) == causal)
  const float* wq = (const float*)d_in[3];
  // d_in[4] wk, d_in[5] wv: dead in the reference forward (cache never written)
  const float* wo = (const float*)d_in[6];
  const float* ck = (const float*)d_in[7];
  const float* cv = (const float*)d_in[8];

  __bf16* q_ws = (__bf16*)d_ws;  // (B,S,NH,HD) bf16 = 33.5 MB (only ws use)

  gemm_bt<0, 1><<<dim3(32, 32), 256, 0, stream>>>(x, wq, q_ws, freqs);
  attn_fwd<<<dim3(32, 32, 2), 256, 0, stream>>>(q_ws, ck, cv);
  gemm_bt<1, 0><<<dim3(32, 32), 256, 0, stream>>>(q_ws, wo, (float*)d_out, nullptr);
}

// Round 3
// 1096.888 us; speedup vs baseline: 1.4875x; 1.2592x over previous
//
#include <hip/hip_runtime.h>

// Attention_26250840113588 — round 5: attack the 80%-idle latency bound in
// attn_fwd (MfmaUtil 4.1 / VALUBusy 14 / HBM 3.3 / conflicts ~6% -> all idle).
// One schedule change, three coordinated parts:
//  1) 128 q-rows per block (2 row-blocks per wave): staging per MFMA halved
//     (block-iters 33792 -> 17408), per-wave ILP doubled; fully-masked
//     row-blocks skipped (rb active iff kt <= 2*qt+rb).
//  2) Double-buffered K/V LDS, ONE barrier per iter: next tile's global loads
//     issue before compute (latency hidden under QK/softmax/PV), cvt+ds_write
//     to the alternate buffer after compute.
//  3) Ks re-layout [64][128] chunk-XOR swizzle (chunk = (hd>>3)^(kv&7)):
//     b128 writes conflict-free, reads 2-way (free); shrinks Ks so the
//     double-buffered total (32+36.9+9.2 = 78.1 KB) fits 2 blocks/CU.
// Vs keeps the round-4 blk-XOR 72-stride layout (proven, 2-way).
// GEMMs unchanged this round.
//
// Pipeline: gemm_bt<0,1> (Q=x@wq^T*rope, bf16 out) -> attn_fwd (in-place)
//           -> gemm_bt<1,0> (out=O@wo^T, fp32 out)

typedef __attribute__((ext_vector_type(8))) __bf16 bf16x8;
typedef __attribute__((ext_vector_type(4))) float f32x4;

#define S_LEN 2048
#define DMODEL 4096
#define NKV 8
#define HD 128

__device__ __forceinline__ bf16x8 cvt8(const float* __restrict__ p) {
  float4 f0 = *(const float4*)p, f1 = *(const float4*)(p + 4);
  bf16x8 v;
  v[0] = (__bf16)f0.x; v[1] = (__bf16)f0.y; v[2] = (__bf16)f0.z; v[3] = (__bf16)f0.w;
  v[4] = (__bf16)f1.x; v[5] = (__bf16)f1.y; v[6] = (__bf16)f1.z; v[7] = (__bf16)f1.w;
  return v;
}

__device__ __forceinline__ bf16x8 cvt8r(float4 f0, float4 f1) {
  bf16x8 v;
  v[0] = (__bf16)f0.x; v[1] = (__bf16)f0.y; v[2] = (__bf16)f0.z; v[3] = (__bf16)f0.w;
  v[4] = (__bf16)f1.x; v[5] = (__bf16)f1.y; v[6] = (__bf16)f1.z; v[7] = (__bf16)f1.w;
  return v;
}

// ---------------- GEMM: C[M,N] = A[M,K] @ Bw[N,K]^T (M=N=K=4096) ----------------
// (unchanged from round 4)
template <int A_BF16, int EPI>
__global__ __launch_bounds__(256) void gemm_bt(
    const void* __restrict__ Av, const float* __restrict__ Bw,
    void* __restrict__ Cv, const float* __restrict__ freqs) {
  __shared__ __attribute__((aligned(16))) __bf16 As[128 * 72];  // [m][k] stride 72
  __shared__ __attribute__((aligned(16))) __bf16 Bs[128 * 72];  // [n][k] stride 72
  const int t = threadIdx.x;
  const int wave = t >> 6, lane = t & 63;
  const int l15 = lane & 15, quad = lane >> 4;
  const int wm = wave >> 1, wn = wave & 1;
  const int m0 = blockIdx.y * 128, n0 = blockIdx.x * 128;
  f32x4 acc[4][4] = {};
  for (int k0 = 0; k0 < DMODEL; k0 += 64) {
#pragma unroll
    for (int i = 0; i < 4; ++i) {  // 128 rows x 64 cols, 8 elems/thread
      int c = i * 256 + t;
      int r = c >> 3, col8 = (c & 7) * 8;
      if (A_BF16) {
        *(float4*)&As[r * 72 + col8] =
            *(const float4*)&((const __bf16*)Av)[(size_t)(m0 + r) * DMODEL + k0 + col8];
      } else {
        *(bf16x8*)&As[r * 72 + col8] =
            cvt8(&((const float*)Av)[(size_t)(m0 + r) * DMODEL + k0 + col8]);
      }
      *(bf16x8*)&Bs[r * 72 + col8] =
          cvt8(&Bw[(size_t)(n0 + r) * DMODEL + k0 + col8]);
    }
    __syncthreads();
#pragma unroll
    for (int ks = 0; ks < 2; ++ks) {
      bf16x8 af[4], bfr[4];
#pragma unroll
      for (int i = 0; i < 4; ++i) {
        af[i]  = *(const bf16x8*)&As[(wm * 64 + i * 16 + l15) * 72 + ks * 32 + quad * 8];
        bfr[i] = *(const bf16x8*)&Bs[(wn * 64 + i * 16 + l15) * 72 + ks * 32 + quad * 8];
      }
#pragma unroll
      for (int mi = 0; mi < 4; ++mi)
#pragma unroll
        for (int ni = 0; ni < 4; ++ni)
          acc[mi][ni] = __builtin_amdgcn_mfma_f32_16x16x32_bf16(
              af[mi], bfr[ni], acc[mi][ni], 0, 0, 0);
    }
    __syncthreads();
  }
#pragma unroll
  for (int mi = 0; mi < 4; ++mi) {
    int rowb = m0 + wm * 64 + mi * 16 + quad * 4;
#pragma unroll
    for (int ni = 0; ni < 4; ++ni) {
      int col = n0 + wn * 64 + ni * 16 + l15;
#pragma unroll
      for (int r = 0; r < 4; ++r) {
        float v = acc[mi][ni][r];
        if (EPI == 1) {
          int s = (rowb + r) & (S_LEN - 1);
          v *= freqs[s * 64 + (col & 63)];
          ((__bf16*)Cv)[(size_t)(rowb + r) * DMODEL + col] = (__bf16)v;
        } else {
          ((float*)Cv)[(size_t)(rowb + r) * DMODEL + col] = v;
        }
      }
    }
  }
}

// ---------------- Flash attention (causal, GQA), Q/O in-place bf16 ----------------
// Block: (qt, h, b); qt tiles of 128 q-rows. 4 waves; wave owns rows
// {rb*64 + wave*16 .. +16} for rb in {0,1}. KV tiles of 64, kt <= 2*qt+1,
// row-block rb active iff kt <= 2*qt+rb.
//
// Ks[buf][kv][hd] (64x128, chunk-XOR swizzled): element (kv,hd) at
//   kv*128 + (((hd>>3) ^ (kv&7))<<3) + (hd&7)
//   write: b128, per-instr chunk = (lane&15)^(kv&7) -> 16 distinct -> free
//   read:  QK^T B-frag, kv varies per lane -> chunk spread over 8 banks (2-way)
// Vs[buf][hd][kv] (128x72, round-4 blk-XOR): element (kv,hd) at
//   hd*72 + ((kv>>3) ^ (hd>>4))*8 + (kv&7)
// Ps[wave][q][kv] stride 72 (per-wave, reused across rb/iters; same-wave LDS
//   ops are in-order and the compiler orders may-alias accesses).
__global__ __launch_bounds__(256, 2) void attn_fwd(
    __bf16* __restrict__ QO, const float* __restrict__ K,
    const float* __restrict__ V) {
  __shared__ __attribute__((aligned(16))) __bf16 Ks[2][64 * 128];
  __shared__ __attribute__((aligned(16))) __bf16 Vs[2][128 * 72];
  __shared__ __attribute__((aligned(16))) __bf16 Ps[4][16 * 72];
  const int qt = blockIdx.x, h = blockIdx.y, b = blockIdx.z;
  const int g = h >> 2;  // NREP = 4
  const int t = threadIdx.x, wave = t >> 6, lane = t & 63;
  const int l15 = lane & 15, quad = lane >> 4;
  const int kx = l15 & 7;

  // Q fragments for both row-blocks
  bf16x8 qf[2][4];
#pragma unroll
  for (int rb = 0; rb < 2; ++rb) {
    const __bf16* qb =
        QO + (size_t)(b * S_LEN + qt * 128 + rb * 64 + wave * 16 + l15) * DMODEL + h * HD;
#pragma unroll
    for (int kk = 0; kk < 4; ++kk) qf[rb][kk] = *(const bf16x8*)&qb[kk * 32 + quad * 8];
  }
  f32x4 of[2][8] = {};
  float m_r[2][4], l_r[2][4];
#pragma unroll
  for (int rb = 0; rb < 2; ++rb)
#pragma unroll
    for (int r = 0; r < 4; ++r) { m_r[rb][r] = -1e30f; l_r[rb][r] = 0.f; }

  const float* kbase = K + ((size_t)b * S_LEN * NKV + g) * HD;
  const float* vbase = V + ((size_t)b * S_LEN * NKV + g) * HD;
  const float scale = 0.08838834764831845f;  // 1/sqrt(128)
  const int KTMAX = 2 * qt + 1;

  // per-thread staging coords: i-th pass covers row r=(i*256+t)>>4, col8=((i*256+t)&15)*8
  float4 kre[8], vre[8];

  auto LOADT = [&](int kt) {
    const float* kr = kbase + (size_t)(kt * 64) * (NKV * HD);
    const float* vr = vbase + (size_t)(kt * 64) * (NKV * HD);
#pragma unroll
    for (int i = 0; i < 4; ++i) {
      int c = i * 256 + t, r = c >> 4, col8 = (c & 15) * 8;
      const float* kp = &kr[(size_t)r * (NKV * HD) + col8];
      const float* vp = &vr[(size_t)r * (NKV * HD) + col8];
      kre[2 * i]     = *(const float4*)kp;
      kre[2 * i + 1] = *(const float4*)(kp + 4);
      vre[2 * i]     = *(const float4*)vp;
      vre[2 * i + 1] = *(const float4*)(vp + 4);
    }
  };
  auto WRITET = [&](int d) {
#pragma unroll
    for (int i = 0; i < 4; ++i) {
      int c = i * 256 + t, r = c >> 4, col8 = (c & 15) * 8;
      // K: swizzled b128 store
      *(bf16x8*)&Ks[d][r * 128 + (((col8 >> 3) ^ (r & 7)) << 3)] =
          cvt8r(kre[2 * i], kre[2 * i + 1]);
      // V: transpose scatter with round-4 blk-XOR
      bf16x8 vv = cvt8r(vre[2 * i], vre[2 * i + 1]);
      const int rblk = r >> 3, rin = r & 7;
#pragma unroll
      for (int j = 0; j < 8; ++j) {
        const int hd = col8 + j;
        const int blk = (rblk ^ (hd >> 4)) & 7;
        Vs[d][hd * 72 + blk * 8 + rin] = vv[j];
      }
    }
  };

  LOADT(0);
  WRITET(0);
  __syncthreads();
  int cur = 0;
  for (int kt = 0; kt <= KTMAX; ++kt) {
    if (kt < KTMAX) LOADT(kt + 1);  // in flight under the compute below
#pragma unroll
    for (int rb = 0; rb < 2; ++rb) {
      if (kt <= 2 * qt + rb) {
        // S = Q K^T  (16 q-rows x 64 kv-cols)
        f32x4 sf[4] = {};
#pragma unroll
        for (int kk = 0; kk < 4; ++kk)
#pragma unroll
          for (int ni = 0; ni < 4; ++ni) {
            const int kv = ni * 16 + l15;
            bf16x8 kf = *(const bf16x8*)&Ks[cur][kv * 128 + (((kk * 4 + quad) ^ kx) << 3)];
            sf[ni] = __builtin_amdgcn_mfma_f32_16x16x32_bf16(qf[rb][kk], kf, sf[ni], 0, 0, 0);
          }
        // online softmax per row
        const int rowg = qt * 128 + rb * 64 + wave * 16 + quad * 4;
#pragma unroll
        for (int r = 0; r < 4; ++r) {
          float sv[4];
#pragma unroll
          for (int ni = 0; ni < 4; ++ni) {
            float v = sf[ni][r] * scale;
            int col = kt * 64 + ni * 16 + l15;
            if (col > rowg + r) v = -1e9f;  // causal mask (== ref's -1e9 add)
            sv[ni] = v;
          }
          float mx = fmaxf(fmaxf(sv[0], sv[1]), fmaxf(sv[2], sv[3]));
#pragma unroll
          for (int off = 1; off < 16; off <<= 1) mx = fmaxf(mx, __shfl_xor(mx, off, 64));
          float mn = fmaxf(m_r[rb][r], mx);
          float alpha = __expf(m_r[rb][r] - mn);
          float sum = 0.f;
#pragma unroll
          for (int ni = 0; ni < 4; ++ni) {
            float p = __expf(sv[ni] - mn);
            sum += p;
            sf[ni][r] = p;
          }
#pragma unroll
          for (int off = 1; off < 16; off <<= 1) sum += __shfl_xor(sum, off, 64);
          l_r[rb][r] = l_r[rb][r] * alpha + sum;
          m_r[rb][r] = mn;
#pragma unroll
          for (int nf = 0; nf < 8; ++nf) of[rb][nf][r] *= alpha;
        }
        // P: C-layout -> per-wave LDS -> A-operand layout
#pragma unroll
        for (int ni = 0; ni < 4; ++ni)
#pragma unroll
          for (int r = 0; r < 4; ++r)
            Ps[wave][(quad * 4 + r) * 72 + ni * 16 + l15] = (__bf16)sf[ni][r];
        asm volatile("s_waitcnt lgkmcnt(0)" ::: "memory");
        // O += P V
#pragma unroll
        for (int kb = 0; kb < 2; ++kb) {
          bf16x8 pf = *(const bf16x8*)&Ps[wave][l15 * 72 + kb * 32 + quad * 8];
#pragma unroll
          for (int nf = 0; nf < 8; ++nf) {
            const int hd = nf * 16 + l15;
            const int blk = ((kb * 4 + quad) ^ (hd >> 4)) & 7;
            bf16x8 vf = *(const bf16x8*)&Vs[cur][hd * 72 + blk * 8];
            of[rb][nf] = __builtin_amdgcn_mfma_f32_16x16x32_bf16(pf, vf, of[rb][nf], 0, 0, 0);
          }
        }
      }
    }
    if (kt < KTMAX) WRITET(cur ^ 1);  // vmcnt drain happens here, off compute path
    __syncthreads();                  // single barrier per iteration
    cur ^= 1;
  }
  // write O over Q (same exclusive slice)
#pragma unroll
  for (int rb = 0; rb < 2; ++rb)
#pragma unroll
    for (int r = 0; r < 4; ++r) {
      float inv = 1.0f / l_r[rb][r];
      size_t row = (size_t)(b * S_LEN + qt * 128 + rb * 64 + wave * 16 + quad * 4 + r);
#pragma unroll
      for (int nf = 0; nf < 8; ++nf)
        QO[row * DMODEL + h * HD + nf * 16 + l15] = (__bf16)(of[rb][nf][r] * inv);
    }
}

extern "C" void kernel_launch(void* const* d_in, const int* in_sizes, int n_in,
                              void* d_out, int out_size, void* d_ws, size_t ws_size,
                              hipStream_t stream) {
  const float* x     = (const float*)d_in[0];
  const float* freqs = (const float*)d_in[1];
  // d_in[2] mask: applied analytically (triu(-1e9, k=1) == causal)
  const float* wq = (const float*)d_in[3];
  // d_in[4] wk, d_in[5] wv: dead in the reference forward (cache never written)
  const float* wo = (const float*)d_in[6];
  const float* ck = (const float*)d_in[7];
  const float* cv = (const float*)d_in[8];

  __bf16* q_ws = (__bf16*)d_ws;  // (B,S,NH,HD) bf16 = 33.5 MB (only ws use)

  gemm_bt<0, 1><<<dim3(32, 32), 256, 0, stream>>>(x, wq, q_ws, freqs);
  attn_fwd<<<dim3(16, 32, 2), 256, 0, stream>>>(q_ws, ck, cv);
  gemm_bt<1, 0><<<dim3(32, 32), 256, 0, stream>>>(q_ws, wo, (float*)d_out, nullptr);
}

// Round 4
// 925.821 us; speedup vs baseline: 1.7624x; 1.1848x over previous
//
#include <hip/hip_runtime.h>

// Attention_26250840113588 — round 6: GEMMs to the m97 global_load_lds
// structure. GEMMs are now the dominant cost (2 x ~334 µs = 411 TF each);
// the measured ladder (m97/m103) says width-16 global_load_lds on a 128²
// tile reaches 874-912 TF. Blocker was fp32 operands -> pre-convert x/wq/wo
// and cache_k/cache_v to bf16 once (~70 µs), then:
//  * gemm_bb: all-bf16, LDS linear dest + pre-swizzled global source
//    (chunk ^= row&7 involution; reads use the same XOR -> ~2-way, free).
//  * attn_fwd<1>: K staged via global_load_lds with pre-swizzled source
//    reproducing the round-5 Ks swizzle exactly (read path unchanged);
//    V loads bf16x8 (half bytes, no cvt).
// ws layout (151.0 MB): [q_ws | x_bf | wq_bf | wo_bf | k_bf | v_bf].
// Host guards on ws_size; falls back to round-5 kernels verbatim if small.

typedef __attribute__((ext_vector_type(8))) __bf16 bf16x8;
typedef __attribute__((ext_vector_type(4))) float f32x4;

#define S_LEN 2048
#define DMODEL 4096
#define NKV 8
#define HD 128

__device__ __forceinline__ bf16x8 cvt8(const float* __restrict__ p) {
  float4 f0 = *(const float4*)p, f1 = *(const float4*)(p + 4);
  bf16x8 v;
  v[0] = (__bf16)f0.x; v[1] = (__bf16)f0.y; v[2] = (__bf16)f0.z; v[3] = (__bf16)f0.w;
  v[4] = (__bf16)f1.x; v[5] = (__bf16)f1.y; v[6] = (__bf16)f1.z; v[7] = (__bf16)f1.w;
  return v;
}

__device__ __forceinline__ bf16x8 cvt8r(float4 f0, float4 f1) {
  bf16x8 v;
  v[0] = (__bf16)f0.x; v[1] = (__bf16)f0.y; v[2] = (__bf16)f0.z; v[3] = (__bf16)f0.w;
  v[4] = (__bf16)f1.x; v[5] = (__bf16)f1.y; v[6] = (__bf16)f1.z; v[7] = (__bf16)f1.w;
  return v;
}

// async global(bf16,16B) -> LDS, linear dest (wave-uniform base + lane*16)
__device__ __forceinline__ void gl_lds16(const __bf16* g, __bf16* l) {
  __builtin_amdgcn_global_load_lds(
      (const __attribute__((address_space(1))) void*)g,
      (__attribute__((address_space(3))) void*)l, 16, 0, 0);
}

// ---------------- fp32 -> bf16 bulk convert (prep) ----------------
__global__ __launch_bounds__(256) void cvt_bf16(
    const float* __restrict__ in, __bf16* __restrict__ out, int n8) {
  int i = blockIdx.x * blockDim.x + threadIdx.x;
  if (i < n8) *(bf16x8*)&out[(size_t)i * 8] = cvt8(&in[(size_t)i * 8]);
}

// ---------------- GEMM (fast): C[M,N] = A[M,K] @ B[N,K]^T, all bf16 ----------------
// m97 structure: 128² tile, BK=64, 256 thr, global_load_lds width 16.
// LDS tiles [128][64] bf16, 16B-chunk XOR swizzle: logical (row, chunk c)
// stored at chunk c ^ (row&7). gload_lds dest is linear; the SOURCE address
// is pre-swizzled (col8 = (lane&7) ^ (lane>>3), since row&7 == lane>>3).
// EPI==1: bf16 out, fused rope scale. EPI==0: fp32 out.
template <int EPI>
__global__ __launch_bounds__(256) void gemm_bb(
    const __bf16* __restrict__ A, const __bf16* __restrict__ B,
    void* __restrict__ Cv, const float* __restrict__ freqs) {
  __shared__ __attribute__((aligned(16))) __bf16 As[128 * 64];
  __shared__ __attribute__((aligned(16))) __bf16 Bs[128 * 64];
  const int t = threadIdx.x;
  const int wave = t >> 6, lane = t & 63;
  const int l15 = lane & 15, quad = lane >> 4;
  const int wm = wave >> 1, wn = wave & 1;
  const int m0 = blockIdx.y * 128, n0 = blockIdx.x * 128;
  // staging coords (per thread, k0-independent)
  const int sl_chunk0 = wave;            // chunkid = i*4 + wave
  const int sl_rowoff = lane >> 3;       // row = chunkid*8 + (lane>>3)
  const int sl_c8 = (lane & 7) ^ (lane >> 3);  // pre-swizzled source chunk
  f32x4 acc[4][4] = {};
  for (int k0 = 0; k0 < DMODEL; k0 += 64) {
#pragma unroll
    for (int i = 0; i < 4; ++i) {
      const int chunkid = i * 4 + sl_chunk0;
      const int row = chunkid * 8 + sl_rowoff;
      gl_lds16(&A[(size_t)(m0 + row) * DMODEL + k0 + sl_c8 * 8],
               &As[chunkid * 512 + lane * 8]);
      gl_lds16(&B[(size_t)(n0 + row) * DMODEL + k0 + sl_c8 * 8],
               &Bs[chunkid * 512 + lane * 8]);
    }
    __syncthreads();  // drains vmcnt (gload_lds) before LDS reads
#pragma unroll
    for (int ks = 0; ks < 2; ++ks) {
      bf16x8 af[4], bfr[4];
#pragma unroll
      for (int i = 0; i < 4; ++i) {
        const int ar = wm * 64 + i * 16 + l15;
        const int br = wn * 64 + i * 16 + l15;
        af[i]  = *(const bf16x8*)&As[ar * 64 + (((ks * 4 + quad) ^ (ar & 7)) << 3)];
        bfr[i] = *(const bf16x8*)&Bs[br * 64 + (((ks * 4 + quad) ^ (br & 7)) << 3)];
      }
#pragma unroll
      for (int mi = 0; mi < 4; ++mi)
#pragma unroll
        for (int ni = 0; ni < 4; ++ni)
          acc[mi][ni] = __builtin_amdgcn_mfma_f32_16x16x32_bf16(
              af[mi], bfr[ni], acc[mi][ni], 0, 0, 0);
    }
    __syncthreads();
  }
#pragma unroll
  for (int mi = 0; mi < 4; ++mi) {
    int rowb = m0 + wm * 64 + mi * 16 + quad * 4;
#pragma unroll
    for (int ni = 0; ni < 4; ++ni) {
      int col = n0 + wn * 64 + ni * 16 + l15;
#pragma unroll
      for (int r = 0; r < 4; ++r) {
        float v = acc[mi][ni][r];
        if (EPI == 1) {
          int s = (rowb + r) & (S_LEN - 1);
          v *= freqs[s * 64 + (col & 63)];
          ((__bf16*)Cv)[(size_t)(rowb + r) * DMODEL + col] = (__bf16)v;
        } else {
          ((float*)Cv)[(size_t)(rowb + r) * DMODEL + col] = v;
        }
      }
    }
  }
}

// ---------------- GEMM (fallback, round-5 verbatim) ----------------
template <int A_BF16, int EPI>
__global__ __launch_bounds__(256) void gemm_bt(
    const void* __restrict__ Av, const float* __restrict__ Bw,
    void* __restrict__ Cv, const float* __restrict__ freqs) {
  __shared__ __attribute__((aligned(16))) __bf16 As[128 * 72];
  __shared__ __attribute__((aligned(16))) __bf16 Bs[128 * 72];
  const int t = threadIdx.x;
  const int wave = t >> 6, lane = t & 63;
  const int l15 = lane & 15, quad = lane >> 4;
  const int wm = wave >> 1, wn = wave & 1;
  const int m0 = blockIdx.y * 128, n0 = blockIdx.x * 128;
  f32x4 acc[4][4] = {};
  for (int k0 = 0; k0 < DMODEL; k0 += 64) {
#pragma unroll
    for (int i = 0; i < 4; ++i) {
      int c = i * 256 + t;
      int r = c >> 3, col8 = (c & 7) * 8;
      if (A_BF16) {
        *(float4*)&As[r * 72 + col8] =
            *(const float4*)&((const __bf16*)Av)[(size_t)(m0 + r) * DMODEL + k0 + col8];
      } else {
        *(bf16x8*)&As[r * 72 + col8] =
            cvt8(&((const float*)Av)[(size_t)(m0 + r) * DMODEL + k0 + col8]);
      }
      *(bf16x8*)&Bs[r * 72 + col8] =
          cvt8(&Bw[(size_t)(n0 + r) * DMODEL + k0 + col8]);
    }
    __syncthreads();
#pragma unroll
    for (int ks = 0; ks < 2; ++ks) {
      bf16x8 af[4], bfr[4];
#pragma unroll
      for (int i = 0; i < 4; ++i) {
        af[i]  = *(const bf16x8*)&As[(wm * 64 + i * 16 + l15) * 72 + ks * 32 + quad * 8];
        bfr[i] = *(const bf16x8*)&Bs[(wn * 64 + i * 16 + l15) * 72 + ks * 32 + quad * 8];
      }
#pragma unroll
      for (int mi = 0; mi < 4; ++mi)
#pragma unroll
        for (int ni = 0; ni < 4; ++ni)
          acc[mi][ni] = __builtin_amdgcn_mfma_f32_16x16x32_bf16(
              af[mi], bfr[ni], acc[mi][ni], 0, 0, 0);
    }
    __syncthreads();
  }
#pragma unroll
  for (int mi = 0; mi < 4; ++mi) {
    int rowb = m0 + wm * 64 + mi * 16 + quad * 4;
#pragma unroll
    for (int ni = 0; ni < 4; ++ni) {
      int col = n0 + wn * 64 + ni * 16 + l15;
#pragma unroll
      for (int r = 0; r < 4; ++r) {
        float v = acc[mi][ni][r];
        if (EPI == 1) {
          int s = (rowb + r) & (S_LEN - 1);
          v *= freqs[s * 64 + (col & 63)];
          ((__bf16*)Cv)[(size_t)(rowb + r) * DMODEL + col] = (__bf16)v;
        } else {
          ((float*)Cv)[(size_t)(rowb + r) * DMODEL + col] = v;
        }
      }
    }
  }
}

// ---------------- Flash attention (causal, GQA), Q/O in-place bf16 ----------------
// Structure from round 5 (128 q-rows/block, dbuf K/V, 1 barrier/iter).
// KVBF=1: K/V are bf16; K staged via global_load_lds, pre-swizzled source
//         reproducing the same Ks layout; V loads bf16x8.
// KVBF=0: round-5 fp32 path verbatim.
// Ks[buf][kv][hd]: element (kv,hd) at kv*128 + (((hd>>3) ^ (kv&7))<<3) + (hd&7)
// Vs[buf][hd][kv]: element (kv,hd) at hd*72 + ((kv>>3) ^ (hd>>4))*8 + (kv&7)
template <int KVBF>
__global__ __launch_bounds__(256, 2) void attn_fwd(
    __bf16* __restrict__ QO, const void* __restrict__ Kp,
    const void* __restrict__ Vp) {
  __shared__ __attribute__((aligned(16))) __bf16 Ks[2][64 * 128];
  __shared__ __attribute__((aligned(16))) __bf16 Vs[2][128 * 72];
  __shared__ __attribute__((aligned(16))) __bf16 Ps[4][16 * 72];
  const int qt = blockIdx.x, h = blockIdx.y, b = blockIdx.z;
  const int g = h >> 2;  // NREP = 4
  const int t = threadIdx.x, wave = t >> 6, lane = t & 63;
  const int l15 = lane & 15, quad = lane >> 4;
  const int kx = l15 & 7;

  bf16x8 qf[2][4];
#pragma unroll
  for (int rb = 0; rb < 2; ++rb) {
    const __bf16* qb =
        QO + (size_t)(b * S_LEN + qt * 128 + rb * 64 + wave * 16 + l15) * DMODEL + h * HD;
#pragma unroll
    for (int kk = 0; kk < 4; ++kk) qf[rb][kk] = *(const bf16x8*)&qb[kk * 32 + quad * 8];
  }
  f32x4 of[2][8] = {};
  float m_r[2][4], l_r[2][4];
#pragma unroll
  for (int rb = 0; rb < 2; ++rb)
#pragma unroll
    for (int r = 0; r < 4; ++r) { m_r[rb][r] = -1e30f; l_r[rb][r] = 0.f; }

  const float* kb32 = (const float*)Kp + ((size_t)b * S_LEN * NKV + g) * HD;
  const float* vb32 = (const float*)Vp + ((size_t)b * S_LEN * NKV + g) * HD;
  const __bf16* kb16 = (const __bf16*)Kp + ((size_t)b * S_LEN * NKV + g) * HD;
  const __bf16* vb16 = (const __bf16*)Vp + ((size_t)b * S_LEN * NKV + g) * HD;
  const float scale = 0.08838834764831845f;  // 1/sqrt(128)
  const int KTMAX = 2 * qt + 1;

  float4 kre[8], vre[8];   // fp32 path staging
  bf16x8 vreb[4];          // bf16 path V staging

  auto ISSUEK = [&](int kt, int d) {  // bf16: async K -> LDS, pre-swizzled src
#pragma unroll
    for (int i = 0; i < 4; ++i) {
      const int chunkid = i * 4 + wave;
      const int kv = chunkid * 4 + (lane >> 4);
      const int hd8 = (lane & 15) ^ (kv & 7);
      gl_lds16(&kb16[(size_t)(kt * 64 + kv) * (NKV * HD) + hd8 * 8],
               &Ks[d][chunkid * 512 + lane * 8]);
    }
  };
  auto LOADV16 = [&](int kt) {
#pragma unroll
    for (int i = 0; i < 4; ++i) {
      int c = i * 256 + t, r = c >> 4, col8 = (c & 15) * 8;
      vreb[i] = *(const bf16x8*)&vb16[(size_t)(kt * 64 + r) * (NKV * HD) + col8];
    }
  };
  auto WRITEV16 = [&](int d) {
#pragma unroll
    for (int i = 0; i < 4; ++i) {
      int c = i * 256 + t, r = c >> 4, col8 = (c & 15) * 8;
      bf16x8 vv = vreb[i];
      const int rblk = r >> 3, rin = r & 7;
#pragma unroll
      for (int j = 0; j < 8; ++j) {
        const int hd = col8 + j;
        const int blk = (rblk ^ (hd >> 4)) & 7;
        Vs[d][hd * 72 + blk * 8 + rin] = vv[j];
      }
    }
  };
  auto LOADT32 = [&](int kt) {
    const float* kr = kb32 + (size_t)(kt * 64) * (NKV * HD);
    const float* vr = vb32 + (size_t)(kt * 64) * (NKV * HD);
#pragma unroll
    for (int i = 0; i < 4; ++i) {
      int c = i * 256 + t, r = c >> 4, col8 = (c & 15) * 8;
      const float* kp = &kr[(size_t)r * (NKV * HD) + col8];
      const float* vp = &vr[(size_t)r * (NKV * HD) + col8];
      kre[2 * i]     = *(const float4*)kp;
      kre[2 * i + 1] = *(const float4*)(kp + 4);
      vre[2 * i]     = *(const float4*)vp;
      vre[2 * i + 1] = *(const float4*)(vp + 4);
    }
  };
  auto WRITET32 = [&](int d) {
#pragma unroll
    for (int i = 0; i < 4; ++i) {
      int c = i * 256 + t, r = c >> 4, col8 = (c & 15) * 8;
      *(bf16x8*)&Ks[d][r * 128 + (((col8 >> 3) ^ (r & 7)) << 3)] =
          cvt8r(kre[2 * i], kre[2 * i + 1]);
      bf16x8 vv = cvt8r(vre[2 * i], vre[2 * i + 1]);
      const int rblk = r >> 3, rin = r & 7;
#pragma unroll
      for (int j = 0; j < 8; ++j) {
        const int hd = col8 + j;
        const int blk = (rblk ^ (hd >> 4)) & 7;
        Vs[d][hd * 72 + blk * 8 + rin] = vv[j];
      }
    }
  };

  // prologue: stage tile 0
  if (KVBF) {
    ISSUEK(0, 0);
    LOADV16(0);
    WRITEV16(0);
  } else {
    LOADT32(0);
    WRITET32(0);
  }
  __syncthreads();  // drains gload_lds vmcnt + LDS writes
  int cur = 0;
  for (int kt = 0; kt <= KTMAX; ++kt) {
    if (kt < KTMAX) {  // prefetch next tile (async / registers)
      if (KVBF) {
        ISSUEK(kt + 1, cur ^ 1);
        LOADV16(kt + 1);
      } else {
        LOADT32(kt + 1);
      }
    }
#pragma unroll
    for (int rb = 0; rb < 2; ++rb) {
      if (kt <= 2 * qt + rb) {
        // S = Q K^T
        f32x4 sf[4] = {};
#pragma unroll
        for (int kk = 0; kk < 4; ++kk)
#pragma unroll
          for (int ni = 0; ni < 4; ++ni) {
            const int kv = ni * 16 + l15;
            bf16x8 kf = *(const bf16x8*)&Ks[cur][kv * 128 + (((kk * 4 + quad) ^ kx) << 3)];
            sf[ni] = __builtin_amdgcn_mfma_f32_16x16x32_bf16(qf[rb][kk], kf, sf[ni], 0, 0, 0);
          }
        // online softmax
        const int rowg = qt * 128 + rb * 64 + wave * 16 + quad * 4;
#pragma unroll
        for (int r = 0; r < 4; ++r) {
          float sv[4];
#pragma unroll
          for (int ni = 0; ni < 4; ++ni) {
            float v = sf[ni][r] * scale;
            int col = kt * 64 + ni * 16 + l15;
            if (col > rowg + r) v = -1e9f;
            sv[ni] = v;
          }
          float mx = fmaxf(fmaxf(sv[0], sv[1]), fmaxf(sv[2], sv[3]));
#pragma unroll
          for (int off = 1; off < 16; off <<= 1) mx = fmaxf(mx, __shfl_xor(mx, off, 64));
          float mn = fmaxf(m_r[rb][r], mx);
          float alpha = __expf(m_r[rb][r] - mn);
          float sum = 0.f;
#pragma unroll
          for (int ni = 0; ni < 4; ++ni) {
            float p = __expf(sv[ni] - mn);
            sum += p;
            sf[ni][r] = p;
          }
#pragma unroll
          for (int off = 1; off < 16; off <<= 1) sum += __shfl_xor(sum, off, 64);
          l_r[rb][r] = l_r[rb][r] * alpha + sum;
          m_r[rb][r] = mn;
#pragma unroll
          for (int nf = 0; nf < 8; ++nf) of[rb][nf][r] *= alpha;
        }
        // P -> per-wave LDS -> A-operand layout
#pragma unroll
        for (int ni = 0; ni < 4; ++ni)
#pragma unroll
          for (int r = 0; r < 4; ++r)
            Ps[wave][(quad * 4 + r) * 72 + ni * 16 + l15] = (__bf16)sf[ni][r];
        asm volatile("s_waitcnt lgkmcnt(0)" ::: "memory");
        // O += P V
#pragma unroll
        for (int kb = 0; kb < 2; ++kb) {
          bf16x8 pf = *(const bf16x8*)&Ps[wave][l15 * 72 + kb * 32 + quad * 8];
#pragma unroll
          for (int nf = 0; nf < 8; ++nf) {
            const int hd = nf * 16 + l15;
            const int blk = ((kb * 4 + quad) ^ (hd >> 4)) & 7;
            bf16x8 vf = *(const bf16x8*)&Vs[cur][hd * 72 + blk * 8];
            of[rb][nf] = __builtin_amdgcn_mfma_f32_16x16x32_bf16(pf, vf, of[rb][nf], 0, 0, 0);
          }
        }
      }
    }
    if (kt < KTMAX) {
      if (KVBF) WRITEV16(cur ^ 1);
      else      WRITET32(cur ^ 1);
    }
    __syncthreads();  // single barrier: drains gload_lds K + LDS V writes
    cur ^= 1;
  }
  // write O over Q
#pragma unroll
  for (int rb = 0; rb < 2; ++rb)
#pragma unroll
    for (int r = 0; r < 4; ++r) {
      float inv = 1.0f / l_r[rb][r];
      size_t row = (size_t)(b * S_LEN + qt * 128 + rb * 64 + wave * 16 + quad * 4 + r);
#pragma unroll
      for (int nf = 0; nf < 8; ++nf)
        QO[row * DMODEL + h * HD + nf * 16 + l15] = (__bf16)(of[rb][nf][r] * inv);
    }
}

extern "C" void kernel_launch(void* const* d_in, const int* in_sizes, int n_in,
                              void* d_out, int out_size, void* d_ws, size_t ws_size,
                              hipStream_t stream) {
  const float* x     = (const float*)d_in[0];
  const float* freqs = (const float*)d_in[1];
  // d_in[2] mask: applied analytically (triu(-1e9, k=1) == causal)
  const float* wq = (const float*)d_in[3];
  // d_in[4] wk, d_in[5] wv: dead in the reference forward (cache never written)
  const float* wo = (const float*)d_in[6];
  const float* ck = (const float*)d_in[7];
  const float* cv = (const float*)d_in[8];

  __bf16* q_ws = (__bf16*)d_ws;  // (B,S,NH,HD) bf16 = 33.55 MB
  const size_t NE = (size_t)DMODEL * DMODEL;          // 16.78M elems (x/wq/wo)
  const size_t NKVE = (size_t)2 * S_LEN * NKV * HD;   // 4.19M elems (ck/cv)
  const size_t NEED = (NE * 4 + NKVE * 2) * sizeof(__bf16) + NE * sizeof(__bf16);
  // = q_ws + x_bf + wq_bf + wo_bf + k_bf + v_bf = 151.0 MB

  if (ws_size >= NEED) {
    __bf16* x_bf  = q_ws + NE;
    __bf16* wq_bf = q_ws + 2 * NE;
    __bf16* wo_bf = q_ws + 3 * NE;
    __bf16* k_bf  = q_ws + 4 * NE;
    __bf16* v_bf  = k_bf + NKVE;
    const int n8w = (int)(NE / 8), n8kv = (int)(NKVE / 8);
    cvt_bf16<<<dim3(n8w / 256), 256, 0, stream>>>(x, x_bf, n8w);
    cvt_bf16<<<dim3(n8w / 256), 256, 0, stream>>>(wq, wq_bf, n8w);
    cvt_bf16<<<dim3(n8w / 256), 256, 0, stream>>>(wo, wo_bf, n8w);
    cvt_bf16<<<dim3(n8kv / 256), 256, 0, stream>>>(ck, k_bf, n8kv);
    cvt_bf16<<<dim3(n8kv / 256), 256, 0, stream>>>(cv, v_bf, n8kv);
    gemm_bb<1><<<dim3(32, 32), 256, 0, stream>>>(x_bf, wq_bf, q_ws, freqs);
    attn_fwd<1><<<dim3(16, 32, 2), 256, 0, stream>>>(q_ws, k_bf, v_bf);
    gemm_bb<0><<<dim3(32, 32), 256, 0, stream>>>(q_ws, wo_bf, (float*)d_out, nullptr);
  } else {
    // fallback: round-5 path (fp32 operands, reg-staged cvt)
    gemm_bt<0, 1><<<dim3(32, 32), 256, 0, stream>>>(x, wq, q_ws, freqs);
    attn_fwd<0><<<dim3(16, 32, 2), 256, 0, stream>>>(q_ws, ck, cv);
    gemm_bt<1, 0><<<dim3(32, 32), 256, 0, stream>>>(q_ws, wo, (float*)d_out, nullptr);
  }
}